// Round 7
// baseline (1725.889 us; speedup 1.0000x reference)
//
#include <hip/hip_runtime.h>
#include <hip/hip_bf16.h>
#include <math.h>

// Problem constants (shapes fixed by the reference)
#define BB   2
#define NN   16
#define EXTC 64
#define SS   1024          // N*EXT
#define DD   512
#define FFD  2048
#define HH   8
#define DHD  64
#define KW   31
#define LL   6
#define BSROWS (BB*SS)     // 2048 tokens
#define LN_EPS 1e-5f

// GEMM epilogue modes
#define EPI_STORE    0   // out fp32 = acc + bias
#define EPI_SILU_BF  1   // out bf16 = silu(acc + bias)
#define EPI_ADD      2   // out fp32 = acc + bias + res
#define EPI_ADD_MASK 4   // out fp32 = (acc + bias + res) or 0 where row masked
#define EPI_STORE_BF 5   // out bf16 = acc + bias
#define EPI_PART     6   // partial fp32 (split-K): part[z*M*N + off] = acc

// ---- robust mask decode (first word identifies encoding; pos 0 is True) ---
__device__ __forceinline__ int mask_val(const void* m, int i) {
    unsigned int w0 = *(const unsigned int*)m;
    if (w0 == 0x01010101u) return ((const unsigned char*)m)[i];          // bool bytes
    if (w0 == 0x3F803F80u) return (((const unsigned short*)m)[i] != 0);  // bf16
    if (w0 == 0x3F800000u) return (((const float*)m)[i] != 0.0f);        // f32
    return (((const int*)m)[i] != 0);                                    // int32
}

__device__ __forceinline__ float sigmoidf_(float x) { return 1.0f / (1.0f + __expf(-x)); }

// fp32 -> bf16 round-to-nearest-even
__device__ __forceinline__ unsigned short f2bf_(float x) {
    unsigned int u = __float_as_uint(x);
    u += 0x7FFF + ((u >> 16) & 1);
    return (unsigned short)(u >> 16);
}
__device__ __forceinline__ float bf2f_(unsigned short b) {
    return __uint_as_float(((unsigned int)b) << 16);
}

typedef __attribute__((ext_vector_type(8))) short bf16x8;
typedef __attribute__((ext_vector_type(4))) float f32x4;

// ---------------- LayerNorm over D=512, one block (256 thr) per row --------
__global__ __launch_bounds__(256) void ln_kernel(
    const float* __restrict__ in, const float* __restrict__ g,
    const float* __restrict__ b, unsigned short* __restrict__ out)
{
    int row = blockIdx.x;
    int t = threadIdx.x;
    const float* ip = in + (size_t)row * DD;
    float v0 = ip[t], v1 = ip[t + 256];
    float s = v0 + v1, ss = v0 * v0 + v1 * v1;
    #pragma unroll
    for (int o = 32; o; o >>= 1) { s += __shfl_down(s, o); ss += __shfl_down(ss, o); }
    __shared__ float sh[8];
    int wid = t >> 6, lane = t & 63;
    if (lane == 0) { sh[wid] = s; sh[4 + wid] = ss; }
    __syncthreads();
    float S = sh[0] + sh[1] + sh[2] + sh[3];
    float Q = sh[4] + sh[5] + sh[6] + sh[7];
    float m = S * (1.0f / DD);
    float rs = rsqrtf(Q * (1.0f / DD) - m * m + LN_EPS);
    out[(size_t)row * DD + t]       = f2bf_((v0 - m) * rs * g[t] + b[t]);
    out[(size_t)row * DD + t + 256] = f2bf_((v1 - m) * rs * g[t + 256] + b[t + 256]);
}

// ---------------- split-K reduce + residual + LN -> bf16 -------------------
// h = 0.5*(p0+p1+bias) + res;  A = h;  Ybf = LN(h; g,b)
__global__ __launch_bounds__(256) void reduce_ln_kernel(
    const float* __restrict__ part, const float* __restrict__ bias,
    const float* __restrict__ res, float* __restrict__ A,
    const float* __restrict__ g, const float* __restrict__ b,
    unsigned short* __restrict__ Ybf)
{
    int row = blockIdx.x, t = threadIdx.x;
    size_t o0 = (size_t)row * DD + t, o1 = o0 + 256;
    const int MN = BSROWS * DD;
    float h0 = 0.5f * (part[o0] + part[MN + o0] + bias[t])       + res[o0];
    float h1 = 0.5f * (part[o1] + part[MN + o1] + bias[t + 256]) + res[o1];
    A[o0] = h0; A[o1] = h1;
    float s = h0 + h1, ss = h0 * h0 + h1 * h1;
    #pragma unroll
    for (int o = 32; o; o >>= 1) { s += __shfl_down(s, o); ss += __shfl_down(ss, o); }
    __shared__ float sh[8];
    int wid = t >> 6, lane = t & 63;
    if (lane == 0) { sh[wid] = s; sh[4 + wid] = ss; }
    __syncthreads();
    float S = sh[0] + sh[1] + sh[2] + sh[3];
    float Q = sh[4] + sh[5] + sh[6] + sh[7];
    float m = S * (1.0f / DD);
    float rs = rsqrtf(Q * (1.0f / DD) - m * m + LN_EPS);
    Ybf[o0] = f2bf_((h0 - m) * rs * g[t] + b[t]);
    Ybf[o1] = f2bf_((h1 - m) * rs * g[t + 256] + b[t + 256]);
}

// ---------------- split-K reduce + residual + finalLN + nextLN -------------
__global__ __launch_bounds__(256) void reduce_lnln_kernel(
    const float* __restrict__ part, const float* __restrict__ bias,
    float* __restrict__ A,
    const float* __restrict__ fing, const float* __restrict__ finb,
    const float* __restrict__ g2, const float* __restrict__ b2,
    unsigned short* __restrict__ Ybf, int last, float* __restrict__ outp)
{
    int row = blockIdx.x, t = threadIdx.x;
    size_t o0 = (size_t)row * DD + t, o1 = o0 + 256;
    const int MN = BSROWS * DD;
    float h0 = 0.5f * (part[o0] + part[MN + o0] + bias[t])       + A[o0];
    float h1 = 0.5f * (part[o1] + part[MN + o1] + bias[t + 256]) + A[o1];
    __shared__ float sh[8];
    int wid = t >> 6, lane = t & 63;
    {
        float s = h0 + h1, ss = h0 * h0 + h1 * h1;
        #pragma unroll
        for (int o = 32; o; o >>= 1) { s += __shfl_down(s, o); ss += __shfl_down(ss, o); }
        if (lane == 0) { sh[wid] = s; sh[4 + wid] = ss; }
    }
    __syncthreads();
    float S = sh[0] + sh[1] + sh[2] + sh[3];
    float Q = sh[4] + sh[5] + sh[6] + sh[7];
    float m = S * (1.0f / DD);
    float rs = rsqrtf(Q * (1.0f / DD) - m * m + LN_EPS);
    float f0 = (h0 - m) * rs * fing[t] + finb[t];
    float f1 = (h1 - m) * rs * fing[t + 256] + finb[t + 256];
    A[o0] = f0; A[o1] = f1;
    if (last) {
        int c = row & 63, bn = row >> 6;
        if (c < 60) {
            size_t oo = ((size_t)(bn * 60 + c)) * DD + t;
            outp[oo] = f0; outp[oo + 256] = f1;
        }
        return;
    }
    __syncthreads();
    {
        float s = f0 + f1, ss = f0 * f0 + f1 * f1;
        #pragma unroll
        for (int o = 32; o; o >>= 1) { s += __shfl_down(s, o); ss += __shfl_down(ss, o); }
        if (lane == 0) { sh[wid] = s; sh[4 + wid] = ss; }
    }
    __syncthreads();
    float S2 = sh[0] + sh[1] + sh[2] + sh[3];
    float Q2 = sh[4] + sh[5] + sh[6] + sh[7];
    float m2 = S2 * (1.0f / DD);
    float rs2 = rsqrtf(Q2 * (1.0f / DD) - m2 * m2 + LN_EPS);
    Ybf[o0] = f2bf_((f0 - m2) * rs2 * g2[t] + b2[t]);
    Ybf[o1] = f2bf_((f1 - m2) * rs2 * g2[t + 256] + b2[t + 256]);
}

// ---------------- weight pre-transpose: fp32 [K,N] -> bf16 [N,K] -----------
// One launch converts all 8 weights x 6 layers. grid = (1472, 6).
#define WARENA_LSTRIDE 6029312   // bf16 elems per layer
__global__ __launch_bounds__(256) void pretrans_kernel(
    const float* __restrict__ w0, const float* __restrict__ w1,
    const float* __restrict__ w2, const float* __restrict__ w3,
    const float* __restrict__ w4, const float* __restrict__ w5,
    const float* __restrict__ w6, const float* __restrict__ w7,
    unsigned short* __restrict__ dst)
{
    const int starts[8] = {0, 256, 512, 704, 768, 896, 960, 1216};
    const int kdim[8]   = {512, 2048, 512, 512, 512, 512, 512, 2048};
    const int ndim[8]   = {2048, 512, 1536, 512, 1024, 512, 2048, 512};
    const int dstoff[8] = {0, 1048576, 2097152, 2883584, 3145728, 3670016, 3932160, 4980736};
    const float* wlist[8] = {w0, w1, w2, w3, w4, w5, w6, w7};
    int layer = blockIdx.y;
    int tile = blockIdx.x;
    int wi = 0;
    #pragma unroll
    for (int i = 7; i >= 1; --i) if (tile >= starts[i]) { wi = i; break; }
    int lt = tile - starts[wi];
    int K = kdim[wi], N = ndim[wi];
    int nT = N >> 6;
    int tk = lt / nT, tn = lt - tk * nT;
    const float* src = wlist[wi] + (size_t)layer * K * N;
    unsigned short* d = dst + (size_t)layer * WARENA_LSTRIDE + dstoff[wi];
    __shared__ float Sm[64][65];
    int t = threadIdx.x;
    int c = t & 63, r4 = t >> 6;
    #pragma unroll
    for (int u = 0; u < 16; ++u) {
        int row = u * 4 + r4;
        Sm[row][c] = src[(size_t)(tk * 64 + row) * N + tn * 64 + c];
    }
    __syncthreads();
    #pragma unroll
    for (int p = 0; p < 4; ++p) {
        int nrow = p * 16 + (t >> 4);
        int koff = (t & 15) * 4;
        uint2 pk;
        pk.x = (unsigned int)f2bf_(Sm[koff + 0][nrow]) | ((unsigned int)f2bf_(Sm[koff + 1][nrow]) << 16);
        pk.y = (unsigned int)f2bf_(Sm[koff + 2][nrow]) | ((unsigned int)f2bf_(Sm[koff + 3][nrow]) << 16);
        *(uint2*)&d[(size_t)(tn * 64 + nrow) * K + tk * 64 + koff] = pk;
    }
}

// ---------------- bf16 MFMA GEMM, 64x64 tile, BK=64, register prefetch -----
#define GSTR 72   // LDS row stride in bf16 elems (64 + 8 pad)
template<bool WT>
__global__ __launch_bounds__(256) void gemm2_kernel(
    const unsigned short* __restrict__ A, const void* __restrict__ Wv,
    const float* __restrict__ bias, const float* __restrict__ res,
    const void* __restrict__ maskraw,
    float* __restrict__ outf, unsigned short* __restrict__ outb,
    float* __restrict__ part, int M, int N, int Kd, int mode)
{
    __shared__ unsigned short As[64 * GSTR];
    __shared__ unsigned short Bs[64 * GSTR];
    int t = threadIdx.x, lane = t & 63, wave = t >> 6;
    int wr = wave >> 1, wc = wave & 1;
    int l15 = lane & 15, l4 = lane >> 4;
    int row0 = blockIdx.y * 64, col0 = blockIdx.x * 64;
    int kPer = Kd / gridDim.z;
    int k0 = blockIdx.z * kPer;
    int iters = kPer >> 6;
    int ar = t >> 2, ak = (t & 3) * 16;
    int wn = t & 63, wk0 = (t >> 6) * 16;

    f32x4 zero = {0.f, 0.f, 0.f, 0.f};
    f32x4 acc[2][2];
    acc[0][0] = zero; acc[0][1] = zero; acc[1][0] = zero; acc[1][1] = zero;

    uint4 aR0, aR1, wR0, wR1;
    float wF[16];
    {
        const unsigned short* ap = A + (size_t)(row0 + ar) * Kd + k0 + ak;
        aR0 = *(const uint4*)ap; aR1 = *(const uint4*)(ap + 8);
        if constexpr (WT) {
            const unsigned short* wp = (const unsigned short*)Wv + (size_t)(col0 + ar) * Kd + k0 + ak;
            wR0 = *(const uint4*)wp; wR1 = *(const uint4*)(wp + 8);
        } else {
            const float* wp = (const float*)Wv + (size_t)(k0 + wk0) * N + col0 + wn;
            #pragma unroll
            for (int kk = 0; kk < 16; ++kk) wF[kk] = wp[(size_t)kk * N];
        }
    }
    for (int it = 0; it < iters; ++it) {
        __syncthreads();
        *(uint4*)&As[ar * GSTR + ak]     = aR0;
        *(uint4*)&As[ar * GSTR + ak + 8] = aR1;
        if constexpr (WT) {
            *(uint4*)&Bs[ar * GSTR + ak]     = wR0;
            *(uint4*)&Bs[ar * GSTR + ak + 8] = wR1;
        } else {
            union { unsigned short u16[16]; uint4 q[2]; } pk;
            #pragma unroll
            for (int kk = 0; kk < 16; ++kk) pk.u16[kk] = f2bf_(wF[kk]);
            uint4* dstp = (uint4*)&Bs[wn * GSTR + wk0];
            dstp[0] = pk.q[0];
            dstp[1] = pk.q[1];
        }
        __syncthreads();
        if (it + 1 < iters) {
            int kn = k0 + (it + 1) * 64;
            const unsigned short* ap = A + (size_t)(row0 + ar) * Kd + kn + ak;
            aR0 = *(const uint4*)ap; aR1 = *(const uint4*)(ap + 8);
            if constexpr (WT) {
                const unsigned short* wp = (const unsigned short*)Wv + (size_t)(col0 + ar) * Kd + kn + ak;
                wR0 = *(const uint4*)wp; wR1 = *(const uint4*)(wp + 8);
            } else {
                const float* wp = (const float*)Wv + (size_t)(kn + wk0) * N + col0 + wn;
                #pragma unroll
                for (int kk = 0; kk < 16; ++kk) wF[kk] = wp[(size_t)kk * N];
            }
        }
        #pragma unroll
        for (int s = 0; s < 2; ++s) {
            bf16x8 af0 = *(const bf16x8*)&As[(wr * 32 + l15) * GSTR + s * 32 + l4 * 8];
            bf16x8 af1 = *(const bf16x8*)&As[(wr * 32 + 16 + l15) * GSTR + s * 32 + l4 * 8];
            bf16x8 bf0 = *(const bf16x8*)&Bs[(wc * 32 + l15) * GSTR + s * 32 + l4 * 8];
            bf16x8 bf1 = *(const bf16x8*)&Bs[(wc * 32 + 16 + l15) * GSTR + s * 32 + l4 * 8];
            acc[0][0] = __builtin_amdgcn_mfma_f32_16x16x32_bf16(af0, bf0, acc[0][0], 0, 0, 0);
            acc[0][1] = __builtin_amdgcn_mfma_f32_16x16x32_bf16(af0, bf1, acc[0][1], 0, 0, 0);
            acc[1][0] = __builtin_amdgcn_mfma_f32_16x16x32_bf16(af1, bf0, acc[1][0], 0, 0, 0);
            acc[1][1] = __builtin_amdgcn_mfma_f32_16x16x32_bf16(af1, bf1, acc[1][1], 0, 0, 0);
        }
    }
    #pragma unroll
    for (int i = 0; i < 2; i++) {
        #pragma unroll
        for (int j = 0; j < 2; j++) {
            int colb = col0 + wc * 32 + j * 16 + l15;
            #pragma unroll
            for (int r = 0; r < 4; r++) {
                int row = row0 + wr * 32 + i * 16 + l4 * 4 + r;
                size_t off = (size_t)row * N + colb;
                float v = acc[i][j][r];
                if (mode == EPI_PART) { part[(size_t)blockIdx.z * M * N + off] = v; continue; }
                v += bias[colb];
                if (mode == EPI_SILU_BF)       outb[off] = f2bf_(v * sigmoidf_(v));
                else if (mode == EPI_STORE_BF) outb[off] = f2bf_(v);
                else if (mode == EPI_ADD)      outf[off] = v + res[off];
                else if (mode == EPI_ADD_MASK) {
                    v = v + res[off];
                    if (!mask_val(maskraw, row)) v = 0.0f;
                    outf[off] = v;
                }
                else                           outf[off] = v;
            }
        }
    }
}

// ---------------- bf16 MFMA GEMM, 128x64 tile, BK=64 (WT path only) --------
// Wave tile 64x32: 4x2 accumulators; per K-iter 16 MFMA : 12 ds_read_b128
// (vs 8:8 in gemm2) — better LDS economy, half the barriers per output elem.
// Grid: (N/64, M/128). Used for the M=2048 big-N GEMMs (w1, qkv).
__global__ __launch_bounds__(256) void gemm3_kernel(
    const unsigned short* __restrict__ A, const unsigned short* __restrict__ W,
    const float* __restrict__ bias, unsigned short* __restrict__ outb,
    int N, int Kd, int mode)
{
    __shared__ unsigned short As[128 * GSTR];
    __shared__ unsigned short Bs[64 * GSTR];
    int t = threadIdx.x, lane = t & 63, wave = t >> 6;
    int wr = wave >> 1, wc = wave & 1;
    int l15 = lane & 15, l4 = lane >> 4;
    int row0 = blockIdx.y * 128, col0 = blockIdx.x * 64;
    int iters = Kd >> 6;
    int ar = t >> 1, ak = (t & 1) * 32;    // A: 128 rows, 2 thr/row, 32 elems each
    int wn = t & 63, wk = (t >> 6) * 16;   // B: 64 rows, 4 thr/row, 16 elems each

    f32x4 zero = {0.f, 0.f, 0.f, 0.f};
    f32x4 acc[4][2];
    #pragma unroll
    for (int i = 0; i < 4; i++) { acc[i][0] = zero; acc[i][1] = zero; }

    uint4 aR[4], wR[2];
    {
        const unsigned short* ap = A + (size_t)(row0 + ar) * Kd + ak;
        aR[0] = *(const uint4*)ap;        aR[1] = *(const uint4*)(ap + 8);
        aR[2] = *(const uint4*)(ap + 16); aR[3] = *(const uint4*)(ap + 24);
        const unsigned short* wp = W + (size_t)(col0 + wn) * Kd + wk;
        wR[0] = *(const uint4*)wp; wR[1] = *(const uint4*)(wp + 8);
    }
    for (int it = 0; it < iters; ++it) {
        __syncthreads();
        {
            uint4* dstp = (uint4*)&As[ar * GSTR + ak];
            dstp[0] = aR[0]; dstp[1] = aR[1]; dstp[2] = aR[2]; dstp[3] = aR[3];
            uint4* dstw = (uint4*)&Bs[wn * GSTR + wk];
            dstw[0] = wR[0]; dstw[1] = wR[1];
        }
        __syncthreads();
        if (it + 1 < iters) {
            int kn = (it + 1) * 64;
            const unsigned short* ap = A + (size_t)(row0 + ar) * Kd + kn + ak;
            aR[0] = *(const uint4*)ap;        aR[1] = *(const uint4*)(ap + 8);
            aR[2] = *(const uint4*)(ap + 16); aR[3] = *(const uint4*)(ap + 24);
            const unsigned short* wp = W + (size_t)(col0 + wn) * Kd + kn + wk;
            wR[0] = *(const uint4*)wp; wR[1] = *(const uint4*)(wp + 8);
        }
        #pragma unroll
        for (int s = 0; s < 2; ++s) {
            bf16x8 bf0 = *(const bf16x8*)&Bs[(wc * 32 + l15) * GSTR + s * 32 + l4 * 8];
            bf16x8 bf1 = *(const bf16x8*)&Bs[(wc * 32 + 16 + l15) * GSTR + s * 32 + l4 * 8];
            #pragma unroll
            for (int i = 0; i < 4; i++) {
                bf16x8 af = *(const bf16x8*)&As[(wr * 64 + i * 16 + l15) * GSTR + s * 32 + l4 * 8];
                acc[i][0] = __builtin_amdgcn_mfma_f32_16x16x32_bf16(af, bf0, acc[i][0], 0, 0, 0);
                acc[i][1] = __builtin_amdgcn_mfma_f32_16x16x32_bf16(af, bf1, acc[i][1], 0, 0, 0);
            }
        }
    }
    #pragma unroll
    for (int i = 0; i < 4; i++) {
        #pragma unroll
        for (int j = 0; j < 2; j++) {
            int colb = col0 + wc * 32 + j * 16 + l15;
            float bia = bias[colb];
            #pragma unroll
            for (int r = 0; r < 4; r++) {
                int row = row0 + wr * 64 + i * 16 + l4 * 4 + r;
                float v = acc[i][j][r] + bia;
                size_t off = (size_t)row * N + colb;
                if (mode == EPI_SILU_BF) outb[off] = f2bf_(v * sigmoidf_(v));
                else                     outb[off] = f2bf_(v);
            }
        }
    }
}

// ---------------- fused p1 GEMM + GLU (WT path only) -----------------------
__global__ __launch_bounds__(256) void gemm_p1glu_kernel(
    const unsigned short* __restrict__ A, const unsigned short* __restrict__ Wp,
    const float* __restrict__ p1b, unsigned short* __restrict__ outb)
{
    __shared__ unsigned short As[64 * GSTR];
    __shared__ unsigned short Bs[128 * GSTR];
    int t = threadIdx.x, lane = t & 63, wave = t >> 6;
    int wr = wave >> 1, wc = wave & 1;
    int l15 = lane & 15, l4 = lane >> 4;
    int row0 = blockIdx.y * 64, g0 = blockIdx.x * 64;
    int ar = t >> 2, ak = (t & 3) * 16;

    f32x4 zero = {0.f, 0.f, 0.f, 0.f};
    f32x4 acca[2][2], accg[2][2];
    acca[0][0] = zero; acca[0][1] = zero; acca[1][0] = zero; acca[1][1] = zero;
    accg[0][0] = zero; accg[0][1] = zero; accg[1][0] = zero; accg[1][1] = zero;

    uint4 aR0, aR1, bA0, bA1, bG0, bG1;
    {
        const unsigned short* ap = A + (size_t)(row0 + ar) * DD + ak;
        aR0 = *(const uint4*)ap; aR1 = *(const uint4*)(ap + 8);
        const unsigned short* wa = Wp + (size_t)(g0 + ar) * DD + ak;
        bA0 = *(const uint4*)wa; bA1 = *(const uint4*)(wa + 8);
        const unsigned short* wg = Wp + (size_t)(g0 + 512 + ar) * DD + ak;
        bG0 = *(const uint4*)wg; bG1 = *(const uint4*)(wg + 8);
    }
    for (int it = 0; it < 8; ++it) {
        __syncthreads();
        *(uint4*)&As[ar * GSTR + ak]            = aR0;
        *(uint4*)&As[ar * GSTR + ak + 8]        = aR1;
        *(uint4*)&Bs[ar * GSTR + ak]            = bA0;
        *(uint4*)&Bs[ar * GSTR + ak + 8]        = bA1;
        *(uint4*)&Bs[(64 + ar) * GSTR + ak]     = bG0;
        *(uint4*)&Bs[(64 + ar) * GSTR + ak + 8] = bG1;
        __syncthreads();
        if (it + 1 < 8) {
            int kn = (it + 1) * 64;
            const unsigned short* ap = A + (size_t)(row0 + ar) * DD + kn + ak;
            aR0 = *(const uint4*)ap; aR1 = *(const uint4*)(ap + 8);
            const unsigned short* wa = Wp + (size_t)(g0 + ar) * DD + kn + ak;
            bA0 = *(const uint4*)wa; bA1 = *(const uint4*)(wa + 8);
            const unsigned short* wg = Wp + (size_t)(g0 + 512 + ar) * DD + kn + ak;
            bG0 = *(const uint4*)wg; bG1 = *(const uint4*)(wg + 8);
        }
        #pragma unroll
        for (int s = 0; s < 2; ++s) {
            bf16x8 af0 = *(const bf16x8*)&As[(wr * 32 + l15) * GSTR + s * 32 + l4 * 8];
            bf16x8 af1 = *(const bf16x8*)&As[(wr * 32 + 16 + l15) * GSTR + s * 32 + l4 * 8];
            bf16x8 ba0 = *(const bf16x8*)&Bs[(wc * 32 + l15) * GSTR + s * 32 + l4 * 8];
            bf16x8 ba1 = *(const bf16x8*)&Bs[(wc * 32 + 16 + l15) * GSTR + s * 32 + l4 * 8];
            bf16x8 bg0 = *(const bf16x8*)&Bs[(64 + wc * 32 + l15) * GSTR + s * 32 + l4 * 8];
            bf16x8 bg1 = *(const bf16x8*)&Bs[(64 + wc * 32 + 16 + l15) * GSTR + s * 32 + l4 * 8];
            acca[0][0] = __builtin_amdgcn_mfma_f32_16x16x32_bf16(af0, ba0, acca[0][0], 0, 0, 0);
            acca[0][1] = __builtin_amdgcn_mfma_f32_16x16x32_bf16(af0, ba1, acca[0][1], 0, 0, 0);
            acca[1][0] = __builtin_amdgcn_mfma_f32_16x16x32_bf16(af1, ba0, acca[1][0], 0, 0, 0);
            acca[1][1] = __builtin_amdgcn_mfma_f32_16x16x32_bf16(af1, ba1, acca[1][1], 0, 0, 0);
            accg[0][0] = __builtin_amdgcn_mfma_f32_16x16x32_bf16(af0, bg0, accg[0][0], 0, 0, 0);
            accg[0][1] = __builtin_amdgcn_mfma_f32_16x16x32_bf16(af0, bg1, accg[0][1], 0, 0, 0);
            accg[1][0] = __builtin_amdgcn_mfma_f32_16x16x32_bf16(af1, bg0, accg[1][0], 0, 0, 0);
            accg[1][1] = __builtin_amdgcn_mfma_f32_16x16x32_bf16(af1, bg1, accg[1][1], 0, 0, 0);
        }
    }
    #pragma unroll
    for (int i = 0; i < 2; i++) {
        #pragma unroll
        for (int j = 0; j < 2; j++) {
            int col = g0 + wc * 32 + j * 16 + l15;
            float ba = p1b[col], bg = p1b[col + 512];
            #pragma unroll
            for (int r = 0; r < 4; r++) {
                int row = row0 + wr * 32 + i * 16 + l4 * 4 + r;
                float a = acca[i][j][r] + ba;
                float gt = accg[i][j][r] + bg;
                outb[(size_t)row * DD + col] = f2bf_(a * sigmoidf_(gt));
            }
        }
    }
}

// ---------------- MFMA flash attention (bf16 in, bf16 out) -----------------
#define QSTR 72   // 64 + 8 pad (bf16 elems)
__global__ __launch_bounds__(256) void attn_mfma_kernel(
    const unsigned short* __restrict__ qkv, const void* __restrict__ maskraw,
    const int* __restrict__ lah_ptr, unsigned short* __restrict__ o)
{
    __shared__ unsigned short Qs[64 * QSTR];
    __shared__ unsigned short Ks[64 * QSTR];
    __shared__ unsigned short Vt[64 * QSTR];
    __shared__ unsigned short Ps[64 * QSTR];
    int idx = blockIdx.x;
    int qc = idx & 15;
    int h  = (idx >> 4) & 7;
    int b  = idx >> 7;
    int t  = threadIdx.x;
    int wave = t >> 6, lane = t & 63;
    int l15 = lane & 15, g = lane >> 4;
    int lah = lah_ptr[0];
    int lim = EXTC - lah;
    size_t base = (size_t)b * SS * 3 * DD;   // bf16 elems
    int ldr = t >> 2;            // 0..63 (position)
    int ldc = (t & 3) * 16;      // dim offset: 0,16,32,48

    {
        const unsigned short* gp = qkv + base + (size_t)(qc * 64 + ldr) * (3 * DD) + h * DHD + ldc;
        *(uint4*)&Qs[ldr * QSTR + ldc]     = *(const uint4*)gp;
        *(uint4*)&Qs[ldr * QSTR + ldc + 8] = *(const uint4*)(gp + 8);
    }
    f32x4 accO[4];
    f32x4 zero = {0.f, 0.f, 0.f, 0.f};
    #pragma unroll
    for (int j = 0; j < 4; j++) accO[j] = zero;
    float m[4], l[4];
    #pragma unroll
    for (int r = 0; r < 4; r++) { m[r] = -INFINITY; l[r] = 0.0f; }

    for (int kc = 0; kc <= qc; ++kc) {
        {
            const unsigned short* kp = qkv + base + (size_t)(kc * 64 + ldr) * (3 * DD) + DD + h * DHD + ldc;
            *(uint4*)&Ks[ldr * QSTR + ldc]     = *(const uint4*)kp;
            *(uint4*)&Ks[ldr * QSTR + ldc + 8] = *(const uint4*)(kp + 8);
        }
        {
            const unsigned short* vp = qkv + base + (size_t)(kc * 64 + ldr) * (3 * DD) + 2 * DD + h * DHD + ldc;
            union { uint4 q[2]; unsigned short u16[16]; } vv;
            vv.q[0] = *(const uint4*)vp;
            vv.q[1] = *(const uint4*)(vp + 8);
            #pragma unroll
            for (int u = 0; u < 16; u++)
                Vt[(ldc + u) * QSTR + ldr] = vv.u16[u];
        }
        __syncthreads();
        bf16x8 aq0 = *(const bf16x8*)&Qs[(wave * 16 + l15) * QSTR + g * 8];
        bf16x8 aq1 = *(const bf16x8*)&Qs[(wave * 16 + l15) * QSTR + 32 + g * 8];
        f32x4 sacc[4];
        #pragma unroll
        for (int j = 0; j < 4; j++) {
            bf16x8 bk0 = *(const bf16x8*)&Ks[(j * 16 + l15) * QSTR + g * 8];
            bf16x8 bk1 = *(const bf16x8*)&Ks[(j * 16 + l15) * QSTR + 32 + g * 8];
            sacc[j] = __builtin_amdgcn_mfma_f32_16x16x32_bf16(aq0, bk0, zero, 0, 0, 0);
            sacc[j] = __builtin_amdgcn_mfma_f32_16x16x32_bf16(aq1, bk1, sacc[j], 0, 0, 0);
        }
        bool curr = (kc == qc);
        #pragma unroll
        for (int j = 0; j < 4; ++j) {
            int kpos = j * 16 + l15;
            bool ok = (curr || (kpos < lim)) && (mask_val(maskraw, b * SS + kc * 64 + kpos) != 0);
            #pragma unroll
            for (int r = 0; r < 4; r++)
                sacc[j][r] = ok ? sacc[j][r] * 0.125f : -1e30f;
        }
        #pragma unroll
        for (int r = 0; r < 4; ++r) {
            float rv = fmaxf(fmaxf(sacc[0][r], sacc[1][r]), fmaxf(sacc[2][r], sacc[3][r]));
            rv = fmaxf(rv, __shfl_xor(rv, 1));
            rv = fmaxf(rv, __shfl_xor(rv, 2));
            rv = fmaxf(rv, __shfl_xor(rv, 4));
            rv = fmaxf(rv, __shfl_xor(rv, 8));
            float mn = fmaxf(m[r], rv);
            float alpha = __expf(m[r] - mn);
            float p0 = __expf(sacc[0][r] - mn), p1 = __expf(sacc[1][r] - mn);
            float p2 = __expf(sacc[2][r] - mn), p3 = __expf(sacc[3][r] - mn);
            float ps = p0 + p1 + p2 + p3;
            ps += __shfl_xor(ps, 1);
            ps += __shfl_xor(ps, 2);
            ps += __shfl_xor(ps, 4);
            ps += __shfl_xor(ps, 8);
            l[r] = l[r] * alpha + ps;
            m[r] = mn;
            #pragma unroll
            for (int j = 0; j < 4; j++) accO[j][r] *= alpha;
            int qrow = wave * 16 + g * 4 + r;
            Ps[qrow * QSTR +  0 + l15] = f2bf_(p0);
            Ps[qrow * QSTR + 16 + l15] = f2bf_(p1);
            Ps[qrow * QSTR + 32 + l15] = f2bf_(p2);
            Ps[qrow * QSTR + 48 + l15] = f2bf_(p3);
        }
        __syncthreads();
        bf16x8 ap0 = *(const bf16x8*)&Ps[(wave * 16 + l15) * QSTR + g * 8];
        bf16x8 ap1 = *(const bf16x8*)&Ps[(wave * 16 + l15) * QSTR + 32 + g * 8];
        #pragma unroll
        for (int j = 0; j < 4; j++) {
            bf16x8 bv0 = *(const bf16x8*)&Vt[(j * 16 + l15) * QSTR + g * 8];
            bf16x8 bv1 = *(const bf16x8*)&Vt[(j * 16 + l15) * QSTR + 32 + g * 8];
            accO[j] = __builtin_amdgcn_mfma_f32_16x16x32_bf16(ap0, bv0, accO[j], 0, 0, 0);
            accO[j] = __builtin_amdgcn_mfma_f32_16x16x32_bf16(ap1, bv1, accO[j], 0, 0, 0);
        }
        __syncthreads();
    }
    #pragma unroll
    for (int r = 0; r < 4; r++) {
        float inv = 1.0f / l[r];
        size_t row = (size_t)b * SS + qc * 64 + wave * 16 + g * 4 + r;
        #pragma unroll
        for (int j = 0; j < 4; j++)
            o[row * DD + h * DHD + j * 16 + l15] = f2bf_(accO[j][r] * inv);
    }
}

// ---------------- GLU fallback (fp32 in -> bf16 out) -----------------------
__global__ __launch_bounds__(256) void glu_kernel(
    const float* __restrict__ in, unsigned short* __restrict__ out)
{
    int idx = blockIdx.x * 256 + threadIdx.x;   // BSROWS * 128
    int d4 = (idx & 127) * 4;
    int r = idx >> 7;
    float4 a = *(const float4*)&in[(size_t)r * 2 * DD + d4];
    float4 gt = *(const float4*)&in[(size_t)r * 2 * DD + DD + d4];
    uint2 pk;
    pk.x = (unsigned int)f2bf_(a.x * sigmoidf_(gt.x)) | ((unsigned int)f2bf_(a.y * sigmoidf_(gt.y)) << 16);
    pk.y = (unsigned int)f2bf_(a.z * sigmoidf_(gt.z)) | ((unsigned int)f2bf_(a.w * sigmoidf_(gt.w)) << 16);
    *(uint2*)&out[(size_t)r * DD + d4] = pk;
}

// ---------------- fused depthwise conv K=31 + LN + silu (bf16 in/out) ------
__global__ __launch_bounds__(256) void dwconv_ln_silu_kernel(
    const unsigned short* __restrict__ in, const float* __restrict__ w,
    const float* __restrict__ bias, const float* __restrict__ g,
    const float* __restrict__ be, unsigned short* __restrict__ out)
{
    int t = threadIdx.x;
    int half = t >> 7;
    int row = blockIdx.x * 2 + half;
    int d4 = (t & 127) * 4;
    int s = row & (SS - 1), b = row >> 10;
    float4 acc = *(const float4*)&bias[d4];
    #pragma unroll
    for (int k = 0; k < KW; k++) {
        int sp = s + k - KW / 2;
        if (sp >= 0 && sp < SS) {
            uint2 xv = *(const uint2*)&in[((size_t)b * SS + sp) * DD + d4];
            float4 ww = *(const float4*)&w[k * DD + d4];
            acc.x = fmaf(bf2f_((unsigned short)(xv.x & 0xFFFF)), ww.x, acc.x);
            acc.y = fmaf(bf2f_((unsigned short)(xv.x >> 16)),    ww.y, acc.y);
            acc.z = fmaf(bf2f_((unsigned short)(xv.y & 0xFFFF)), ww.z, acc.z);
            acc.w = fmaf(bf2f_((unsigned short)(xv.y >> 16)),    ww.w, acc.w);
        }
    }
    float sm = acc.x + acc.y + acc.z + acc.w;
    float sq = acc.x * acc.x + acc.y * acc.y + acc.z * acc.z + acc.w * acc.w;
    #pragma unroll
    for (int o = 32; o; o >>= 1) { sm += __shfl_down(sm, o); sq += __shfl_down(sq, o); }
    __shared__ float sh[8];
    int wid = t >> 6, lane = t & 63;
    if (lane == 0) { sh[wid] = sm; sh[4 + wid] = sq; }
    __syncthreads();
    float S = sh[half * 2] + sh[half * 2 + 1];
    float Q = sh[4 + half * 2] + sh[4 + half * 2 + 1];
    float mean = S * (1.0f / DD);
    float rs = rsqrtf(Q * (1.0f / DD) - mean * mean + LN_EPS);
    float4 gg = *(const float4*)&g[d4];
    float4 bb = *(const float4*)&be[d4];
    float y0 = (acc.x - mean) * rs * gg.x + bb.x;
    float y1 = (acc.y - mean) * rs * gg.y + bb.y;
    float y2 = (acc.z - mean) * rs * gg.z + bb.z;
    float y3 = (acc.w - mean) * rs * gg.w + bb.w;
    y0 *= sigmoidf_(y0); y1 *= sigmoidf_(y1); y2 *= sigmoidf_(y2); y3 *= sigmoidf_(y3);
    uint2 pk;
    pk.x = (unsigned int)f2bf_(y0) | ((unsigned int)f2bf_(y1) << 16);
    pk.y = (unsigned int)f2bf_(y2) | ((unsigned int)f2bf_(y3) << 16);
    *(uint2*)&out[(size_t)row * DD + d4] = pk;
}

extern "C" void kernel_launch(void* const* d_in, const int* in_sizes, int n_in,
                              void* d_out, int out_size, void* d_ws, size_t ws_size,
                              hipStream_t stream)
{
    const float* x    = (const float*)d_in[0];
    const void*  mask = d_in[1];
    const int*   lah  = (const int*)d_in[2];
    #define P(i) ((const float*)d_in[i])

    // workspace: 26 MB base; weight arena (69 MB) appended when room permits
    char* wsb = (char*)d_ws;
    float*          A   = (float*)(wsb);                      // 4 MB residual fp32
    unsigned short* Ybf = (unsigned short*)(wsb + (4u<<20));  // 2 MB LN out bf16
    char*           U   = wsb + (6u<<20);                     // 12 MB union
    unsigned short* Db  = (unsigned short*)(wsb + (18u<<20)); // 2 MB glu out bf16
    unsigned short* Dbf = (unsigned short*)(wsb + (22u<<20)); // 2 MB attn out bf16
    float*          Part = (float*)(wsb + (18u<<20));         // 8 MB split-K partials (aliases Db/Dbf window)
    float*          Uf  = (float*)U;                          // pw1 out fp32 (fallback)
    unsigned short* Ub  = (unsigned short*)U;                 // FF hidden / qkv bf16
    unsigned short* Wt  = (unsigned short*)(wsb + (26u<<20)); // 69 MB bf16 [N,K] weights
    bool wt = ws_size >= (100ull << 20);

    if (wt) {
        dim3 gpt(1472, LL);
        pretrans_kernel<<<gpt, 256, 0, stream>>>(P(5), P(7), P(11), P(13), P(17),
                                                 P(23), P(27), P(29), Wt);
    }
    // Wt per-layer offsets (order: ff1w1, ff1w2, wqkv, wo, p1w, p2w, ff2w1, ff2w2)
    const size_t woff[8] = {0, 1048576, 2097152, 2883584, 3145728, 3670016, 3932160, 4980736};

    #define GEMM(grid, Aptr, Wfp, wi, bias, res, mk, of, ob, pt, M_, N_, K_, md)            \
        do { if (wt)                                                                         \
            gemm2_kernel<true><<<grid, 256, 0, stream>>>(Aptr,                               \
                (const void*)(Wt + (size_t)l * WARENA_LSTRIDE + woff[wi]), bias, res, mk,    \
                of, ob, pt, M_, N_, K_, md);                                                 \
        else                                                                                 \
            gemm2_kernel<false><<<grid, 256, 0, stream>>>(Aptr, (const void*)(Wfp), bias,    \
                res, mk, of, ob, pt, M_, N_, K_, md); } while (0)

    // gemm3 (128x64 tile) for the big M=2048 GEMMs on the WT path; gemm2
    // fallback otherwise.
    #define GEMM3(Aptr, Wfp, wi, bias, ob, N_, md, g2grid)                                  \
        do { if (wt)                                                                         \
            gemm3_kernel<<<dim3((N_) / 64, BSROWS / 128), 256, 0, stream>>>(Aptr,            \
                Wt + (size_t)l * WARENA_LSTRIDE + woff[wi], bias, ob, N_, DD, md);           \
        else                                                                                 \
            gemm2_kernel<false><<<g2grid, 256, 0, stream>>>(Aptr, (const void*)(Wfp), bias,  \
                nullptr, nullptr, nullptr, ob, nullptr, BSROWS, N_, DD, md); } while (0)

    dim3 gFF1 (FFD / 64,    BSROWS / 64, 1);   // fallback w1 grid
    dim3 gW2  (DD / 64,     BSROWS / 64, 2);   // 8x32x2 = 512 blocks (split-K)
    dim3 gQKV (3 * DD / 64, BSROWS / 64, 1);   // fallback qkv grid
    dim3 gP1  (2 * DD / 64, BSROWS / 64, 1);   // 16x32 = 512 (fallback)
    dim3 gGLU (DD / 64,     BSROWS / 64, 1);   // 8x32  = 256 (fused p1+glu)
    dim3 gDx  (DD / 64,     BSROWS / 64, 1);   // 8x32  = 256

    for (int l = 0; l < LL; l++) {
        const float* f1g  = P(3)  + (size_t)l * DD;
        const float* f1b  = P(4)  + (size_t)l * DD;
        const float* f1w1 = P(5)  + (size_t)l * DD * FFD;
        const float* f1b1 = P(6)  + (size_t)l * FFD;
        const float* f1w2 = P(7)  + (size_t)l * FFD * DD;
        const float* f1b2 = P(8)  + (size_t)l * DD;
        const float* alg  = P(9)  + (size_t)l * DD;
        const float* alb  = P(10) + (size_t)l * DD;
        const float* wqkv = P(11) + (size_t)l * DD * 3 * DD;
        const float* bqkv = P(12) + (size_t)l * 3 * DD;
        const float* wo   = P(13) + (size_t)l * DD * DD;
        const float* bo   = P(14) + (size_t)l * DD;
        const float* clg  = P(15) + (size_t)l * DD;
        const float* clb  = P(16) + (size_t)l * DD;
        const float* p1w  = P(17) + (size_t)l * DD * 2 * DD;
        const float* p1b  = P(18) + (size_t)l * 2 * DD;
        const float* dww  = P(19) + (size_t)l * KW * DD;
        const float* dwb  = P(20) + (size_t)l * DD;
        const float* cng  = P(21) + (size_t)l * DD;
        const float* cnb  = P(22) + (size_t)l * DD;
        const float* p2w  = P(23) + (size_t)l * DD * DD;
        const float* p2b  = P(24) + (size_t)l * DD;
        const float* f2g  = P(25) + (size_t)l * DD;
        const float* f2b  = P(26) + (size_t)l * DD;
        const float* f2w1 = P(27) + (size_t)l * DD * FFD;
        const float* f2b1 = P(28) + (size_t)l * FFD;
        const float* f2w2 = P(29) + (size_t)l * FFD * DD;
        const float* f2b2 = P(30) + (size_t)l * DD;
        const float* fing = P(31) + (size_t)l * DD;
        const float* finb = P(32) + (size_t)l * DD;

        // FF1: Ybf = LN(h) (layer 0 standalone; else from prev reduce_lnln)
        if (l == 0)
            ln_kernel<<<BSROWS, 256, 0, stream>>>(x, f1g, f1b, Ybf);
        GEMM3(Ybf, f1w1, 0, f1b1, Ub, FFD, EPI_SILU_BF, gFF1);
        GEMM(gW2, Ub, f1w2, 1, nullptr, nullptr, nullptr, nullptr, nullptr, Part,
             BSROWS, DD, FFD, EPI_PART);
        reduce_ln_kernel<<<BSROWS, 256, 0, stream>>>(Part, f1b2, (l == 0) ? x : A,
                                                     A, alg, alb, Ybf);

        // MHSA
        GEMM3(Ybf, wqkv, 2, bqkv, Ub, 3 * DD, EPI_STORE_BF, gQKV);
        attn_mfma_kernel<<<BB * HH * NN, 256, 0, stream>>>(Ub, mask, lah, Dbf);
        GEMM(gDx, Dbf, wo, 3, bo, A, mask, A, nullptr, nullptr,
             BSROWS, DD, DD, EPI_ADD_MASK);

        // Conv module
        ln_kernel<<<BSROWS, 256, 0, stream>>>(A, clg, clb, Ybf);
        if (wt) {
            gemm_p1glu_kernel<<<gGLU, 256, 0, stream>>>(
                Ybf, Wt + (size_t)l * WARENA_LSTRIDE + woff[4], p1b, Db);
        } else {
            gemm2_kernel<false><<<gP1, 256, 0, stream>>>(Ybf, (const void*)p1w, p1b,
                nullptr, nullptr, Uf, nullptr, nullptr, BSROWS, 2 * DD, DD, EPI_STORE);
            glu_kernel<<<BSROWS * DD / 4 / 256, 256, 0, stream>>>(Uf, Db);
        }
        dwconv_ln_silu_kernel<<<BSROWS / 2, 256, 0, stream>>>(Db, dww, dwb, cng, cnb, Ybf);
        GEMM(gDx, Ybf, p2w, 5, p2b, A, nullptr, A, nullptr, nullptr,
             BSROWS, DD, DD, EPI_ADD);

        // FF2
        ln_kernel<<<BSROWS, 256, 0, stream>>>(A, f2g, f2b, Ybf);
        GEMM3(Ybf, f2w1, 6, f2b1, Ub, FFD, EPI_SILU_BF, gFF1);
        GEMM(gW2, Ub, f2w2, 7, nullptr, nullptr, nullptr, nullptr, nullptr, Part,
             BSROWS, DD, FFD, EPI_PART);
        int last = (l == LL - 1);
        reduce_lnln_kernel<<<BSROWS, 256, 0, stream>>>(Part, f2b2, A, fing, finb,
            last ? fing : (P(3) + (size_t)(l + 1) * DD),
            last ? finb : (P(4) + (size_t)(l + 1) * DD),
            Ybf, last, (float*)d_out);
    }
    #undef GEMM
    #undef GEMM3
    #undef P
}

// Round 8
// 1357.492 us; speedup vs baseline: 1.2714x; 1.2714x over previous
//
#include <hip/hip_runtime.h>
#include <hip/hip_bf16.h>
#include <math.h>

// Problem constants (shapes fixed by the reference)
#define BB   2
#define NN   16
#define EXTC 64
#define SS   1024          // N*EXT
#define DD   512
#define FFD  2048
#define HH   8
#define DHD  64
#define KW   31
#define LL   6
#define BSROWS (BB*SS)     // 2048 tokens
#define LN_EPS 1e-5f

// GEMM epilogue modes
#define EPI_STORE    0   // out fp32 = acc + bias
#define EPI_SILU_BF  1   // out bf16 = silu(acc + bias)
#define EPI_ADD      2   // out fp32 = acc + bias + res
#define EPI_ADD_MASK 4   // out fp32 = (acc + bias + res) or 0 where row masked
#define EPI_STORE_BF 5   // out bf16 = acc + bias
#define EPI_PART     6   // partial fp32 (split-K): part[z*M*N + off] = acc

// ---- robust mask decode (first word identifies encoding; pos 0 is True) ---
__device__ __forceinline__ int mask_val(const void* m, int i) {
    unsigned int w0 = *(const unsigned int*)m;
    if (w0 == 0x01010101u) return ((const unsigned char*)m)[i];          // bool bytes
    if (w0 == 0x3F803F80u) return (((const unsigned short*)m)[i] != 0);  // bf16
    if (w0 == 0x3F800000u) return (((const float*)m)[i] != 0.0f);        // f32
    return (((const int*)m)[i] != 0);                                    // int32
}

__device__ __forceinline__ float sigmoidf_(float x) { return 1.0f / (1.0f + __expf(-x)); }

// fp32 -> bf16 round-to-nearest-even
__device__ __forceinline__ unsigned short f2bf_(float x) {
    unsigned int u = __float_as_uint(x);
    u += 0x7FFF + ((u >> 16) & 1);
    return (unsigned short)(u >> 16);
}
__device__ __forceinline__ float bf2f_(unsigned short b) {
    return __uint_as_float(((unsigned int)b) << 16);
}

typedef __attribute__((ext_vector_type(8))) short bf16x8;
typedef __attribute__((ext_vector_type(4))) float f32x4;

// ---------------- LayerNorm over D=512, one block (256 thr) per row --------
__global__ __launch_bounds__(256) void ln_kernel(
    const float* __restrict__ in, const float* __restrict__ g,
    const float* __restrict__ b, unsigned short* __restrict__ out)
{
    int row = blockIdx.x;
    int t = threadIdx.x;
    const float* ip = in + (size_t)row * DD;
    float v0 = ip[t], v1 = ip[t + 256];
    float s = v0 + v1, ss = v0 * v0 + v1 * v1;
    #pragma unroll
    for (int o = 32; o; o >>= 1) { s += __shfl_down(s, o); ss += __shfl_down(ss, o); }
    __shared__ float sh[8];
    int wid = t >> 6, lane = t & 63;
    if (lane == 0) { sh[wid] = s; sh[4 + wid] = ss; }
    __syncthreads();
    float S = sh[0] + sh[1] + sh[2] + sh[3];
    float Q = sh[4] + sh[5] + sh[6] + sh[7];
    float m = S * (1.0f / DD);
    float rs = rsqrtf(Q * (1.0f / DD) - m * m + LN_EPS);
    out[(size_t)row * DD + t]       = f2bf_((v0 - m) * rs * g[t] + b[t]);
    out[(size_t)row * DD + t + 256] = f2bf_((v1 - m) * rs * g[t + 256] + b[t + 256]);
}

// ---------------- split-K reduce + residual + LN -> bf16 -------------------
// h = 0.5*(p0+p1+bias) + res;  A = h;  Ybf = LN(h; g,b)
__global__ __launch_bounds__(256) void reduce_ln_kernel(
    const float* __restrict__ part, const float* __restrict__ bias,
    const float* __restrict__ res, float* __restrict__ A,
    const float* __restrict__ g, const float* __restrict__ b,
    unsigned short* __restrict__ Ybf)
{
    int row = blockIdx.x, t = threadIdx.x;
    size_t o0 = (size_t)row * DD + t, o1 = o0 + 256;
    const int MN = BSROWS * DD;
    float h0 = 0.5f * (part[o0] + part[MN + o0] + bias[t])       + res[o0];
    float h1 = 0.5f * (part[o1] + part[MN + o1] + bias[t + 256]) + res[o1];
    A[o0] = h0; A[o1] = h1;
    float s = h0 + h1, ss = h0 * h0 + h1 * h1;
    #pragma unroll
    for (int o = 32; o; o >>= 1) { s += __shfl_down(s, o); ss += __shfl_down(ss, o); }
    __shared__ float sh[8];
    int wid = t >> 6, lane = t & 63;
    if (lane == 0) { sh[wid] = s; sh[4 + wid] = ss; }
    __syncthreads();
    float S = sh[0] + sh[1] + sh[2] + sh[3];
    float Q = sh[4] + sh[5] + sh[6] + sh[7];
    float m = S * (1.0f / DD);
    float rs = rsqrtf(Q * (1.0f / DD) - m * m + LN_EPS);
    Ybf[o0] = f2bf_((h0 - m) * rs * g[t] + b[t]);
    Ybf[o1] = f2bf_((h1 - m) * rs * g[t + 256] + b[t + 256]);
}

// ---------------- split-K reduce + residual + finalLN + nextLN -------------
__global__ __launch_bounds__(256) void reduce_lnln_kernel(
    const float* __restrict__ part, const float* __restrict__ bias,
    float* __restrict__ A,
    const float* __restrict__ fing, const float* __restrict__ finb,
    const float* __restrict__ g2, const float* __restrict__ b2,
    unsigned short* __restrict__ Ybf, int last, float* __restrict__ outp)
{
    int row = blockIdx.x, t = threadIdx.x;
    size_t o0 = (size_t)row * DD + t, o1 = o0 + 256;
    const int MN = BSROWS * DD;
    float h0 = 0.5f * (part[o0] + part[MN + o0] + bias[t])       + A[o0];
    float h1 = 0.5f * (part[o1] + part[MN + o1] + bias[t + 256]) + A[o1];
    __shared__ float sh[8];
    int wid = t >> 6, lane = t & 63;
    {
        float s = h0 + h1, ss = h0 * h0 + h1 * h1;
        #pragma unroll
        for (int o = 32; o; o >>= 1) { s += __shfl_down(s, o); ss += __shfl_down(ss, o); }
        if (lane == 0) { sh[wid] = s; sh[4 + wid] = ss; }
    }
    __syncthreads();
    float S = sh[0] + sh[1] + sh[2] + sh[3];
    float Q = sh[4] + sh[5] + sh[6] + sh[7];
    float m = S * (1.0f / DD);
    float rs = rsqrtf(Q * (1.0f / DD) - m * m + LN_EPS);
    float f0 = (h0 - m) * rs * fing[t] + finb[t];
    float f1 = (h1 - m) * rs * fing[t + 256] + finb[t + 256];
    A[o0] = f0; A[o1] = f1;
    if (last) {
        int c = row & 63, bn = row >> 6;
        if (c < 60) {
            size_t oo = ((size_t)(bn * 60 + c)) * DD + t;
            outp[oo] = f0; outp[oo + 256] = f1;
        }
        return;
    }
    __syncthreads();
    {
        float s = f0 + f1, ss = f0 * f0 + f1 * f1;
        #pragma unroll
        for (int o = 32; o; o >>= 1) { s += __shfl_down(s, o); ss += __shfl_down(ss, o); }
        if (lane == 0) { sh[wid] = s; sh[4 + wid] = ss; }
    }
    __syncthreads();
    float S2 = sh[0] + sh[1] + sh[2] + sh[3];
    float Q2 = sh[4] + sh[5] + sh[6] + sh[7];
    float m2 = S2 * (1.0f / DD);
    float rs2 = rsqrtf(Q2 * (1.0f / DD) - m2 * m2 + LN_EPS);
    Ybf[o0] = f2bf_((f0 - m2) * rs2 * g2[t] + b2[t]);
    Ybf[o1] = f2bf_((f1 - m2) * rs2 * g2[t + 256] + b2[t + 256]);
}

// ---------------- weight pre-transpose: fp32 [K,N] -> bf16 [N,K] -----------
// One launch converts all 8 weights x 6 layers. grid = (1472, 6).
// float4 loads, padded LDS (2-way max everywhere), 2x b128 stores/thread.
#define WARENA_LSTRIDE 6029312   // bf16 elems per layer
__global__ __launch_bounds__(256) void pretrans_kernel(
    const float* __restrict__ w0, const float* __restrict__ w1,
    const float* __restrict__ w2, const float* __restrict__ w3,
    const float* __restrict__ w4, const float* __restrict__ w5,
    const float* __restrict__ w6, const float* __restrict__ w7,
    unsigned short* __restrict__ dst)
{
    const int starts[8] = {0, 256, 512, 704, 768, 896, 960, 1216};
    const int kdim[8]   = {512, 2048, 512, 512, 512, 512, 512, 2048};
    const int ndim[8]   = {2048, 512, 1536, 512, 1024, 512, 2048, 512};
    const int dstoff[8] = {0, 1048576, 2097152, 2883584, 3145728, 3670016, 3932160, 4980736};
    const float* wlist[8] = {w0, w1, w2, w3, w4, w5, w6, w7};
    int layer = blockIdx.y;
    int tile = blockIdx.x;
    int wi = 0;
    #pragma unroll
    for (int i = 7; i >= 1; --i) if (tile >= starts[i]) { wi = i; break; }
    int lt = tile - starts[wi];
    int K = kdim[wi], N = ndim[wi];
    int nT = N >> 6;
    int tk = lt / nT, tn = lt - tk * nT;
    const float* src = wlist[wi] + (size_t)layer * K * N;
    unsigned short* d = dst + (size_t)layer * WARENA_LSTRIDE + dstoff[wi];
    __shared__ float Sm[64][68];   // [k][n], +4 pad: all phases <=2-way
    int t = threadIdx.x;
    {   // load 64x64 fp32 tile, float4 per thread x4 rows
        int r = t >> 4, c4 = (t & 15) * 4;
        #pragma unroll
        for (int u = 0; u < 4; ++u) {
            int row = u * 16 + r;
            *(float4*)&Sm[row][c4] =
                *(const float4*)&src[(size_t)(tk * 64 + row) * N + tn * 64 + c4];
        }
    }
    __syncthreads();
    {   // store transposed: thread owns (n = t&63, k0 = (t>>6)*16); 32B out
        int n = t & 63, k0 = (t >> 6) * 16;
        union { unsigned short u16[16]; uint4 v[2]; } pk;
        #pragma unroll
        for (int i = 0; i < 16; ++i) pk.u16[i] = f2bf_(Sm[k0 + i][n]);
        uint4* dp = (uint4*)&d[(size_t)(tn * 64 + n) * K + tk * 64 + k0];
        dp[0] = pk.v[0];
        dp[1] = pk.v[1];
    }
}

// ---------------- bf16 MFMA GEMM, 64x64 tile, BK=64, register prefetch -----
#define GSTR 72   // LDS row stride in bf16 elems (64 + 8 pad)
template<bool WT>
__global__ __launch_bounds__(256) void gemm2_kernel(
    const unsigned short* __restrict__ A, const void* __restrict__ Wv,
    const float* __restrict__ bias, const float* __restrict__ res,
    const void* __restrict__ maskraw,
    float* __restrict__ outf, unsigned short* __restrict__ outb,
    float* __restrict__ part, int M, int N, int Kd, int mode)
{
    __shared__ unsigned short As[64 * GSTR];
    __shared__ unsigned short Bs[64 * GSTR];
    int t = threadIdx.x, lane = t & 63, wave = t >> 6;
    int wr = wave >> 1, wc = wave & 1;
    int l15 = lane & 15, l4 = lane >> 4;
    int row0 = blockIdx.y * 64, col0 = blockIdx.x * 64;
    int kPer = Kd / gridDim.z;
    int k0 = blockIdx.z * kPer;
    int iters = kPer >> 6;
    int ar = t >> 2, ak = (t & 3) * 16;
    int wn = t & 63, wk0 = (t >> 6) * 16;

    f32x4 zero = {0.f, 0.f, 0.f, 0.f};
    f32x4 acc[2][2];
    acc[0][0] = zero; acc[0][1] = zero; acc[1][0] = zero; acc[1][1] = zero;

    uint4 aR0, aR1, wR0, wR1;
    float wF[16];
    {
        const unsigned short* ap = A + (size_t)(row0 + ar) * Kd + k0 + ak;
        aR0 = *(const uint4*)ap; aR1 = *(const uint4*)(ap + 8);
        if constexpr (WT) {
            const unsigned short* wp = (const unsigned short*)Wv + (size_t)(col0 + ar) * Kd + k0 + ak;
            wR0 = *(const uint4*)wp; wR1 = *(const uint4*)(wp + 8);
        } else {
            const float* wp = (const float*)Wv + (size_t)(k0 + wk0) * N + col0 + wn;
            #pragma unroll
            for (int kk = 0; kk < 16; ++kk) wF[kk] = wp[(size_t)kk * N];
        }
    }
    for (int it = 0; it < iters; ++it) {
        __syncthreads();
        *(uint4*)&As[ar * GSTR + ak]     = aR0;
        *(uint4*)&As[ar * GSTR + ak + 8] = aR1;
        if constexpr (WT) {
            *(uint4*)&Bs[ar * GSTR + ak]     = wR0;
            *(uint4*)&Bs[ar * GSTR + ak + 8] = wR1;
        } else {
            union { unsigned short u16[16]; uint4 q[2]; } pk;
            #pragma unroll
            for (int kk = 0; kk < 16; ++kk) pk.u16[kk] = f2bf_(wF[kk]);
            uint4* dstp = (uint4*)&Bs[wn * GSTR + wk0];
            dstp[0] = pk.q[0];
            dstp[1] = pk.q[1];
        }
        __syncthreads();
        if (it + 1 < iters) {
            int kn = k0 + (it + 1) * 64;
            const unsigned short* ap = A + (size_t)(row0 + ar) * Kd + kn + ak;
            aR0 = *(const uint4*)ap; aR1 = *(const uint4*)(ap + 8);
            if constexpr (WT) {
                const unsigned short* wp = (const unsigned short*)Wv + (size_t)(col0 + ar) * Kd + kn + ak;
                wR0 = *(const uint4*)wp; wR1 = *(const uint4*)(wp + 8);
            } else {
                const float* wp = (const float*)Wv + (size_t)(kn + wk0) * N + col0 + wn;
                #pragma unroll
                for (int kk = 0; kk < 16; ++kk) wF[kk] = wp[(size_t)kk * N];
            }
        }
        #pragma unroll
        for (int s = 0; s < 2; ++s) {
            bf16x8 af0 = *(const bf16x8*)&As[(wr * 32 + l15) * GSTR + s * 32 + l4 * 8];
            bf16x8 af1 = *(const bf16x8*)&As[(wr * 32 + 16 + l15) * GSTR + s * 32 + l4 * 8];
            bf16x8 bf0 = *(const bf16x8*)&Bs[(wc * 32 + l15) * GSTR + s * 32 + l4 * 8];
            bf16x8 bf1 = *(const bf16x8*)&Bs[(wc * 32 + 16 + l15) * GSTR + s * 32 + l4 * 8];
            acc[0][0] = __builtin_amdgcn_mfma_f32_16x16x32_bf16(af0, bf0, acc[0][0], 0, 0, 0);
            acc[0][1] = __builtin_amdgcn_mfma_f32_16x16x32_bf16(af0, bf1, acc[0][1], 0, 0, 0);
            acc[1][0] = __builtin_amdgcn_mfma_f32_16x16x32_bf16(af1, bf0, acc[1][0], 0, 0, 0);
            acc[1][1] = __builtin_amdgcn_mfma_f32_16x16x32_bf16(af1, bf1, acc[1][1], 0, 0, 0);
        }
    }
    #pragma unroll
    for (int i = 0; i < 2; i++) {
        #pragma unroll
        for (int j = 0; j < 2; j++) {
            int colb = col0 + wc * 32 + j * 16 + l15;
            #pragma unroll
            for (int r = 0; r < 4; r++) {
                int row = row0 + wr * 32 + i * 16 + l4 * 4 + r;
                size_t off = (size_t)row * N + colb;
                float v = acc[i][j][r];
                if (mode == EPI_PART) { part[(size_t)blockIdx.z * M * N + off] = v; continue; }
                v += bias[colb];
                if (mode == EPI_SILU_BF)       outb[off] = f2bf_(v * sigmoidf_(v));
                else if (mode == EPI_STORE_BF) outb[off] = f2bf_(v);
                else if (mode == EPI_ADD)      outf[off] = v + res[off];
                else if (mode == EPI_ADD_MASK) {
                    v = v + res[off];
                    if (!mask_val(maskraw, row)) v = 0.0f;
                    outf[off] = v;
                }
                else                           outf[off] = v;
            }
        }
    }
}

// ---------------- fused p1 GEMM + GLU (WT path only) -----------------------
__global__ __launch_bounds__(256) void gemm_p1glu_kernel(
    const unsigned short* __restrict__ A, const unsigned short* __restrict__ Wp,
    const float* __restrict__ p1b, unsigned short* __restrict__ outb)
{
    __shared__ unsigned short As[64 * GSTR];
    __shared__ unsigned short Bs[128 * GSTR];
    int t = threadIdx.x, lane = t & 63, wave = t >> 6;
    int wr = wave >> 1, wc = wave & 1;
    int l15 = lane & 15, l4 = lane >> 4;
    int row0 = blockIdx.y * 64, g0 = blockIdx.x * 64;
    int ar = t >> 2, ak = (t & 3) * 16;

    f32x4 zero = {0.f, 0.f, 0.f, 0.f};
    f32x4 acca[2][2], accg[2][2];
    acca[0][0] = zero; acca[0][1] = zero; acca[1][0] = zero; acca[1][1] = zero;
    accg[0][0] = zero; accg[0][1] = zero; accg[1][0] = zero; accg[1][1] = zero;

    uint4 aR0, aR1, bA0, bA1, bG0, bG1;
    {
        const unsigned short* ap = A + (size_t)(row0 + ar) * DD + ak;
        aR0 = *(const uint4*)ap; aR1 = *(const uint4*)(ap + 8);
        const unsigned short* wa = Wp + (size_t)(g0 + ar) * DD + ak;
        bA0 = *(const uint4*)wa; bA1 = *(const uint4*)(wa + 8);
        const unsigned short* wg = Wp + (size_t)(g0 + 512 + ar) * DD + ak;
        bG0 = *(const uint4*)wg; bG1 = *(const uint4*)(wg + 8);
    }
    for (int it = 0; it < 8; ++it) {
        __syncthreads();
        *(uint4*)&As[ar * GSTR + ak]            = aR0;
        *(uint4*)&As[ar * GSTR + ak + 8]        = aR1;
        *(uint4*)&Bs[ar * GSTR + ak]            = bA0;
        *(uint4*)&Bs[ar * GSTR + ak + 8]        = bA1;
        *(uint4*)&Bs[(64 + ar) * GSTR + ak]     = bG0;
        *(uint4*)&Bs[(64 + ar) * GSTR + ak + 8] = bG1;
        __syncthreads();
        if (it + 1 < 8) {
            int kn = (it + 1) * 64;
            const unsigned short* ap = A + (size_t)(row0 + ar) * DD + kn + ak;
            aR0 = *(const uint4*)ap; aR1 = *(const uint4*)(ap + 8);
            const unsigned short* wa = Wp + (size_t)(g0 + ar) * DD + kn + ak;
            bA0 = *(const uint4*)wa; bA1 = *(const uint4*)(wa + 8);
            const unsigned short* wg = Wp + (size_t)(g0 + 512 + ar) * DD + kn + ak;
            bG0 = *(const uint4*)wg; bG1 = *(const uint4*)(wg + 8);
        }
        #pragma unroll
        for (int s = 0; s < 2; ++s) {
            bf16x8 af0 = *(const bf16x8*)&As[(wr * 32 + l15) * GSTR + s * 32 + l4 * 8];
            bf16x8 af1 = *(const bf16x8*)&As[(wr * 32 + 16 + l15) * GSTR + s * 32 + l4 * 8];
            bf16x8 ba0 = *(const bf16x8*)&Bs[(wc * 32 + l15) * GSTR + s * 32 + l4 * 8];
            bf16x8 ba1 = *(const bf16x8*)&Bs[(wc * 32 + 16 + l15) * GSTR + s * 32 + l4 * 8];
            bf16x8 bg0 = *(const bf16x8*)&Bs[(64 + wc * 32 + l15) * GSTR + s * 32 + l4 * 8];
            bf16x8 bg1 = *(const bf16x8*)&Bs[(64 + wc * 32 + 16 + l15) * GSTR + s * 32 + l4 * 8];
            acca[0][0] = __builtin_amdgcn_mfma_f32_16x16x32_bf16(af0, ba0, acca[0][0], 0, 0, 0);
            acca[0][1] = __builtin_amdgcn_mfma_f32_16x16x32_bf16(af0, ba1, acca[0][1], 0, 0, 0);
            acca[1][0] = __builtin_amdgcn_mfma_f32_16x16x32_bf16(af1, ba0, acca[1][0], 0, 0, 0);
            acca[1][1] = __builtin_amdgcn_mfma_f32_16x16x32_bf16(af1, ba1, acca[1][1], 0, 0, 0);
            accg[0][0] = __builtin_amdgcn_mfma_f32_16x16x32_bf16(af0, bg0, accg[0][0], 0, 0, 0);
            accg[0][1] = __builtin_amdgcn_mfma_f32_16x16x32_bf16(af0, bg1, accg[0][1], 0, 0, 0);
            accg[1][0] = __builtin_amdgcn_mfma_f32_16x16x32_bf16(af1, bg0, accg[1][0], 0, 0, 0);
            accg[1][1] = __builtin_amdgcn_mfma_f32_16x16x32_bf16(af1, bg1, accg[1][1], 0, 0, 0);
        }
    }
    #pragma unroll
    for (int i = 0; i < 2; i++) {
        #pragma unroll
        for (int j = 0; j < 2; j++) {
            int col = g0 + wc * 32 + j * 16 + l15;
            float ba = p1b[col], bg = p1b[col + 512];
            #pragma unroll
            for (int r = 0; r < 4; r++) {
                int row = row0 + wr * 32 + i * 16 + l4 * 4 + r;
                float a = acca[i][j][r] + ba;
                float gt = accg[i][j][r] + bg;
                outb[(size_t)row * DD + col] = f2bf_(a * sigmoidf_(gt));
            }
        }
    }
}

// ---------------- MFMA flash attention (bf16 in, bf16 out) -----------------
#define QSTR 72   // 64 + 8 pad (bf16 elems)
__global__ __launch_bounds__(256) void attn_mfma_kernel(
    const unsigned short* __restrict__ qkv, const void* __restrict__ maskraw,
    const int* __restrict__ lah_ptr, unsigned short* __restrict__ o)
{
    __shared__ unsigned short Qs[64 * QSTR];
    __shared__ unsigned short Ks[64 * QSTR];
    __shared__ unsigned short Vt[64 * QSTR];
    __shared__ unsigned short Ps[64 * QSTR];
    int idx = blockIdx.x;
    int qc = idx & 15;
    int h  = (idx >> 4) & 7;
    int b  = idx >> 7;
    int t  = threadIdx.x;
    int wave = t >> 6, lane = t & 63;
    int l15 = lane & 15, g = lane >> 4;
    int lah = lah_ptr[0];
    int lim = EXTC - lah;
    size_t base = (size_t)b * SS * 3 * DD;   // bf16 elems
    int ldr = t >> 2;            // 0..63 (position)
    int ldc = (t & 3) * 16;      // dim offset: 0,16,32,48

    {
        const unsigned short* gp = qkv + base + (size_t)(qc * 64 + ldr) * (3 * DD) + h * DHD + ldc;
        *(uint4*)&Qs[ldr * QSTR + ldc]     = *(const uint4*)gp;
        *(uint4*)&Qs[ldr * QSTR + ldc + 8] = *(const uint4*)(gp + 8);
    }
    f32x4 accO[4];
    f32x4 zero = {0.f, 0.f, 0.f, 0.f};
    #pragma unroll
    for (int j = 0; j < 4; j++) accO[j] = zero;
    float m[4], l[4];
    #pragma unroll
    for (int r = 0; r < 4; r++) { m[r] = -INFINITY; l[r] = 0.0f; }

    for (int kc = 0; kc <= qc; ++kc) {
        {
            const unsigned short* kp = qkv + base + (size_t)(kc * 64 + ldr) * (3 * DD) + DD + h * DHD + ldc;
            *(uint4*)&Ks[ldr * QSTR + ldc]     = *(const uint4*)kp;
            *(uint4*)&Ks[ldr * QSTR + ldc + 8] = *(const uint4*)(kp + 8);
        }
        {
            const unsigned short* vp = qkv + base + (size_t)(kc * 64 + ldr) * (3 * DD) + 2 * DD + h * DHD + ldc;
            union { uint4 q[2]; unsigned short u16[16]; } vv;
            vv.q[0] = *(const uint4*)vp;
            vv.q[1] = *(const uint4*)(vp + 8);
            #pragma unroll
            for (int u = 0; u < 16; u++)
                Vt[(ldc + u) * QSTR + ldr] = vv.u16[u];
        }
        __syncthreads();
        bf16x8 aq0 = *(const bf16x8*)&Qs[(wave * 16 + l15) * QSTR + g * 8];
        bf16x8 aq1 = *(const bf16x8*)&Qs[(wave * 16 + l15) * QSTR + 32 + g * 8];
        f32x4 sacc[4];
        #pragma unroll
        for (int j = 0; j < 4; j++) {
            bf16x8 bk0 = *(const bf16x8*)&Ks[(j * 16 + l15) * QSTR + g * 8];
            bf16x8 bk1 = *(const bf16x8*)&Ks[(j * 16 + l15) * QSTR + 32 + g * 8];
            sacc[j] = __builtin_amdgcn_mfma_f32_16x16x32_bf16(aq0, bk0, zero, 0, 0, 0);
            sacc[j] = __builtin_amdgcn_mfma_f32_16x16x32_bf16(aq1, bk1, sacc[j], 0, 0, 0);
        }
        bool curr = (kc == qc);
        #pragma unroll
        for (int j = 0; j < 4; ++j) {
            int kpos = j * 16 + l15;
            bool ok = (curr || (kpos < lim)) && (mask_val(maskraw, b * SS + kc * 64 + kpos) != 0);
            #pragma unroll
            for (int r = 0; r < 4; r++)
                sacc[j][r] = ok ? sacc[j][r] * 0.125f : -1e30f;
        }
        #pragma unroll
        for (int r = 0; r < 4; ++r) {
            float rv = fmaxf(fmaxf(sacc[0][r], sacc[1][r]), fmaxf(sacc[2][r], sacc[3][r]));
            rv = fmaxf(rv, __shfl_xor(rv, 1));
            rv = fmaxf(rv, __shfl_xor(rv, 2));
            rv = fmaxf(rv, __shfl_xor(rv, 4));
            rv = fmaxf(rv, __shfl_xor(rv, 8));
            float mn = fmaxf(m[r], rv);
            float alpha = __expf(m[r] - mn);
            float p0 = __expf(sacc[0][r] - mn), p1 = __expf(sacc[1][r] - mn);
            float p2 = __expf(sacc[2][r] - mn), p3 = __expf(sacc[3][r] - mn);
            float ps = p0 + p1 + p2 + p3;
            ps += __shfl_xor(ps, 1);
            ps += __shfl_xor(ps, 2);
            ps += __shfl_xor(ps, 4);
            ps += __shfl_xor(ps, 8);
            l[r] = l[r] * alpha + ps;
            m[r] = mn;
            #pragma unroll
            for (int j = 0; j < 4; j++) accO[j][r] *= alpha;
            int qrow = wave * 16 + g * 4 + r;
            Ps[qrow * QSTR +  0 + l15] = f2bf_(p0);
            Ps[qrow * QSTR + 16 + l15] = f2bf_(p1);
            Ps[qrow * QSTR + 32 + l15] = f2bf_(p2);
            Ps[qrow * QSTR + 48 + l15] = f2bf_(p3);
        }
        __syncthreads();
        bf16x8 ap0 = *(const bf16x8*)&Ps[(wave * 16 + l15) * QSTR + g * 8];
        bf16x8 ap1 = *(const bf16x8*)&Ps[(wave * 16 + l15) * QSTR + 32 + g * 8];
        #pragma unroll
        for (int j = 0; j < 4; j++) {
            bf16x8 bv0 = *(const bf16x8*)&Vt[(j * 16 + l15) * QSTR + g * 8];
            bf16x8 bv1 = *(const bf16x8*)&Vt[(j * 16 + l15) * QSTR + 32 + g * 8];
            accO[j] = __builtin_amdgcn_mfma_f32_16x16x32_bf16(ap0, bv0, accO[j], 0, 0, 0);
            accO[j] = __builtin_amdgcn_mfma_f32_16x16x32_bf16(ap1, bv1, accO[j], 0, 0, 0);
        }
        __syncthreads();
    }
    #pragma unroll
    for (int r = 0; r < 4; r++) {
        float inv = 1.0f / l[r];
        size_t row = (size_t)b * SS + qc * 64 + wave * 16 + g * 4 + r;
        #pragma unroll
        for (int j = 0; j < 4; j++)
            o[row * DD + h * DHD + j * 16 + l15] = f2bf_(accO[j][r] * inv);
    }
}

// ---------------- GLU fallback (fp32 in -> bf16 out) -----------------------
__global__ __launch_bounds__(256) void glu_kernel(
    const float* __restrict__ in, unsigned short* __restrict__ out)
{
    int idx = blockIdx.x * 256 + threadIdx.x;   // BSROWS * 128
    int d4 = (idx & 127) * 4;
    int r = idx >> 7;
    float4 a = *(const float4*)&in[(size_t)r * 2 * DD + d4];
    float4 gt = *(const float4*)&in[(size_t)r * 2 * DD + DD + d4];
    uint2 pk;
    pk.x = (unsigned int)f2bf_(a.x * sigmoidf_(gt.x)) | ((unsigned int)f2bf_(a.y * sigmoidf_(gt.y)) << 16);
    pk.y = (unsigned int)f2bf_(a.z * sigmoidf_(gt.z)) | ((unsigned int)f2bf_(a.w * sigmoidf_(gt.w)) << 16);
    *(uint2*)&out[(size_t)r * DD + d4] = pk;
}

// ---------------- fused depthwise conv K=31 + LN + silu (bf16 in/out) ------
__global__ __launch_bounds__(256) void dwconv_ln_silu_kernel(
    const unsigned short* __restrict__ in, const float* __restrict__ w,
    const float* __restrict__ bias, const float* __restrict__ g,
    const float* __restrict__ be, unsigned short* __restrict__ out)
{
    int t = threadIdx.x;
    int half = t >> 7;
    int row = blockIdx.x * 2 + half;
    int d4 = (t & 127) * 4;
    int s = row & (SS - 1), b = row >> 10;
    float4 acc = *(const float4*)&bias[d4];
    #pragma unroll
    for (int k = 0; k < KW; k++) {
        int sp = s + k - KW / 2;
        if (sp >= 0 && sp < SS) {
            uint2 xv = *(const uint2*)&in[((size_t)b * SS + sp) * DD + d4];
            float4 ww = *(const float4*)&w[k * DD + d4];
            acc.x = fmaf(bf2f_((unsigned short)(xv.x & 0xFFFF)), ww.x, acc.x);
            acc.y = fmaf(bf2f_((unsigned short)(xv.x >> 16)),    ww.y, acc.y);
            acc.z = fmaf(bf2f_((unsigned short)(xv.y & 0xFFFF)), ww.z, acc.z);
            acc.w = fmaf(bf2f_((unsigned short)(xv.y >> 16)),    ww.w, acc.w);
        }
    }
    float sm = acc.x + acc.y + acc.z + acc.w;
    float sq = acc.x * acc.x + acc.y * acc.y + acc.z * acc.z + acc.w * acc.w;
    #pragma unroll
    for (int o = 32; o; o >>= 1) { sm += __shfl_down(sm, o); sq += __shfl_down(sq, o); }
    __shared__ float sh[8];
    int wid = t >> 6, lane = t & 63;
    if (lane == 0) { sh[wid] = sm; sh[4 + wid] = sq; }
    __syncthreads();
    float S = sh[half * 2] + sh[half * 2 + 1];
    float Q = sh[4 + half * 2] + sh[4 + half * 2 + 1];
    float mean = S * (1.0f / DD);
    float rs = rsqrtf(Q * (1.0f / DD) - mean * mean + LN_EPS);
    float4 gg = *(const float4*)&g[d4];
    float4 bb = *(const float4*)&be[d4];
    float y0 = (acc.x - mean) * rs * gg.x + bb.x;
    float y1 = (acc.y - mean) * rs * gg.y + bb.y;
    float y2 = (acc.z - mean) * rs * gg.z + bb.z;
    float y3 = (acc.w - mean) * rs * gg.w + bb.w;
    y0 *= sigmoidf_(y0); y1 *= sigmoidf_(y1); y2 *= sigmoidf_(y2); y3 *= sigmoidf_(y3);
    uint2 pk;
    pk.x = (unsigned int)f2bf_(y0) | ((unsigned int)f2bf_(y1) << 16);
    pk.y = (unsigned int)f2bf_(y2) | ((unsigned int)f2bf_(y3) << 16);
    *(uint2*)&out[(size_t)row * DD + d4] = pk;
}

extern "C" void kernel_launch(void* const* d_in, const int* in_sizes, int n_in,
                              void* d_out, int out_size, void* d_ws, size_t ws_size,
                              hipStream_t stream)
{
    const float* x    = (const float*)d_in[0];
    const void*  mask = d_in[1];
    const int*   lah  = (const int*)d_in[2];
    #define P(i) ((const float*)d_in[i])

    // workspace: 26 MB base; weight arena (69 MB) appended when room permits
    char* wsb = (char*)d_ws;
    float*          A   = (float*)(wsb);                      // 4 MB residual fp32
    unsigned short* Ybf = (unsigned short*)(wsb + (4u<<20));  // 2 MB LN out bf16
    char*           U   = wsb + (6u<<20);                     // 12 MB union
    unsigned short* Db  = (unsigned short*)(wsb + (18u<<20)); // 2 MB glu out bf16
    unsigned short* Dbf = (unsigned short*)(wsb + (22u<<20)); // 2 MB attn out bf16
    float*          Part = (float*)(wsb + (18u<<20));         // 8 MB split-K partials (aliases Db/Dbf window)
    float*          Uf  = (float*)U;                          // pw1 out fp32 (fallback)
    unsigned short* Ub  = (unsigned short*)U;                 // FF hidden / qkv bf16
    unsigned short* Wt  = (unsigned short*)(wsb + (26u<<20)); // 69 MB bf16 [N,K] weights
    bool wt = ws_size >= (100ull << 20);

    if (wt) {
        dim3 gpt(1472, LL);
        pretrans_kernel<<<gpt, 256, 0, stream>>>(P(5), P(7), P(11), P(13), P(17),
                                                 P(23), P(27), P(29), Wt);
    }
    // Wt per-layer offsets (order: ff1w1, ff1w2, wqkv, wo, p1w, p2w, ff2w1, ff2w2)
    const size_t woff[8] = {0, 1048576, 2097152, 2883584, 3145728, 3670016, 3932160, 4980736};

    #define GEMM(grid, Aptr, Wfp, wi, bias, res, mk, of, ob, pt, M_, N_, K_, md)            \
        do { if (wt)                                                                         \
            gemm2_kernel<true><<<grid, 256, 0, stream>>>(Aptr,                               \
                (const void*)(Wt + (size_t)l * WARENA_LSTRIDE + woff[wi]), bias, res, mk,    \
                of, ob, pt, M_, N_, K_, md);                                                 \
        else                                                                                 \
            gemm2_kernel<false><<<grid, 256, 0, stream>>>(Aptr, (const void*)(Wfp), bias,    \
                res, mk, of, ob, pt, M_, N_, K_, md); } while (0)

    dim3 gFF1 (FFD / 64,    BSROWS / 64, 1);   // 32x32   = 1024 blocks
    dim3 gW2  (DD / 64,     BSROWS / 64, 2);   // 8x32x2  = 512 blocks (split-K)
    dim3 gQKV (3 * DD / 64, BSROWS / 64, 1);   // 24x32   = 768
    dim3 gP1  (2 * DD / 64, BSROWS / 64, 1);   // 16x32   = 512 (fallback)
    dim3 gGLU (DD / 64,     BSROWS / 64, 1);   // 8x32    = 256 (fused p1+glu)
    dim3 gDx  (DD / 64,     BSROWS / 64, 1);   // 8x32    = 256

    for (int l = 0; l < LL; l++) {
        const float* f1g  = P(3)  + (size_t)l * DD;
        const float* f1b  = P(4)  + (size_t)l * DD;
        const float* f1w1 = P(5)  + (size_t)l * DD * FFD;
        const float* f1b1 = P(6)  + (size_t)l * FFD;
        const float* f1w2 = P(7)  + (size_t)l * FFD * DD;
        const float* f1b2 = P(8)  + (size_t)l * DD;
        const float* alg  = P(9)  + (size_t)l * DD;
        const float* alb  = P(10) + (size_t)l * DD;
        const float* wqkv = P(11) + (size_t)l * DD * 3 * DD;
        const float* bqkv = P(12) + (size_t)l * 3 * DD;
        const float* wo   = P(13) + (size_t)l * DD * DD;
        const float* bo   = P(14) + (size_t)l * DD;
        const float* clg  = P(15) + (size_t)l * DD;
        const float* clb  = P(16) + (size_t)l * DD;
        const float* p1w  = P(17) + (size_t)l * DD * 2 * DD;
        const float* p1b  = P(18) + (size_t)l * 2 * DD;
        const float* dww  = P(19) + (size_t)l * KW * DD;
        const float* dwb  = P(20) + (size_t)l * DD;
        const float* cng  = P(21) + (size_t)l * DD;
        const float* cnb  = P(22) + (size_t)l * DD;
        const float* p2w  = P(23) + (size_t)l * DD * DD;
        const float* p2b  = P(24) + (size_t)l * DD;
        const float* f2g  = P(25) + (size_t)l * DD;
        const float* f2b  = P(26) + (size_t)l * DD;
        const float* f2w1 = P(27) + (size_t)l * DD * FFD;
        const float* f2b1 = P(28) + (size_t)l * FFD;
        const float* f2w2 = P(29) + (size_t)l * FFD * DD;
        const float* f2b2 = P(30) + (size_t)l * DD;
        const float* fing = P(31) + (size_t)l * DD;
        const float* finb = P(32) + (size_t)l * DD;

        // FF1: Ybf = LN(h) (layer 0 standalone; else from prev reduce_lnln)
        if (l == 0)
            ln_kernel<<<BSROWS, 256, 0, stream>>>(x, f1g, f1b, Ybf);
        GEMM(gFF1, Ybf, f1w1, 0, f1b1, nullptr, nullptr, nullptr, Ub, nullptr,
             BSROWS, FFD, DD, EPI_SILU_BF);
        GEMM(gW2, Ub, f1w2, 1, nullptr, nullptr, nullptr, nullptr, nullptr, Part,
             BSROWS, DD, FFD, EPI_PART);
        reduce_ln_kernel<<<BSROWS, 256, 0, stream>>>(Part, f1b2, (l == 0) ? x : A,
                                                     A, alg, alb, Ybf);

        // MHSA
        GEMM(gQKV, Ybf, wqkv, 2, bqkv, nullptr, nullptr, nullptr, Ub, nullptr,
             BSROWS, 3 * DD, DD, EPI_STORE_BF);
        attn_mfma_kernel<<<BB * HH * NN, 256, 0, stream>>>(Ub, mask, lah, Dbf);
        GEMM(gDx, Dbf, wo, 3, bo, A, mask, A, nullptr, nullptr,
             BSROWS, DD, DD, EPI_ADD_MASK);

        // Conv module
        ln_kernel<<<BSROWS, 256, 0, stream>>>(A, clg, clb, Ybf);
        if (wt) {
            gemm_p1glu_kernel<<<gGLU, 256, 0, stream>>>(
                Ybf, Wt + (size_t)l * WARENA_LSTRIDE + woff[4], p1b, Db);
        } else {
            gemm2_kernel<false><<<gP1, 256, 0, stream>>>(Ybf, (const void*)p1w, p1b,
                nullptr, nullptr, Uf, nullptr, nullptr, BSROWS, 2 * DD, DD, EPI_STORE);
            glu_kernel<<<BSROWS * DD / 4 / 256, 256, 0, stream>>>(Uf, Db);
        }
        dwconv_ln_silu_kernel<<<BSROWS / 2, 256, 0, stream>>>(Db, dww, dwb, cng, cnb, Ybf);
        GEMM(gDx, Ybf, p2w, 5, p2b, A, nullptr, A, nullptr, nullptr,
             BSROWS, DD, DD, EPI_ADD);

        // FF2
        ln_kernel<<<BSROWS, 256, 0, stream>>>(A, f2g, f2b, Ybf);
        GEMM(gFF1, Ybf, f2w1, 6, f2b1, nullptr, nullptr, nullptr, Ub, nullptr,
             BSROWS, FFD, DD, EPI_SILU_BF);
        GEMM(gW2, Ub, f2w2, 7, nullptr, nullptr, nullptr, nullptr, nullptr, Part,
             BSROWS, DD, FFD, EPI_PART);
        int last = (l == LL - 1);
        reduce_lnln_kernel<<<BSROWS, 256, 0, stream>>>(Part, f2b2, A, fing, finb,
            last ? fing : (P(3) + (size_t)(l + 1) * DD),
            last ? finb : (P(4) + (size_t)(l + 1) * DD),
            Ybf, last, (float*)d_out);
    }
    #undef GEMM
    #undef P
}